// Round 6
// baseline (707.660 us; speedup 1.0000x reference)
//
#include <hip/hip_runtime.h>

// GRU: B=256, T=2048, I=2, H=128. One workgroup (8 waves) per batch element.
// R22 = R20 (verified 628us) + two critical-path shaves. R21 falsified the
// LDS-drain model (halving reads REGRESSED 8%: broadcast reads are cheap,
// 2 waves/SIMD interleave is worth more) -- 8-wave config is the base.
// Step model (~550cyc): read roundtrip ~130 + MFMA chain ~80 + select ~15
// + gate chain ~110 + write tail ~20 + barrier ~90; VALU issue overlaps.
// Shave 1: split K-chain into 2 INDEPENDENT 1-deep MFMAs per gate;
//   select each (first select hides under second MFMA), combine with one
//   i32 add -> removes one MFMA dependency latency (~25-30cyc) for
//   +4 VALU/gate (issue hidden by co-resident wave).
// Shave 2: h127-scaled recurrence (h127 = 127*h): zh127p = fma(z,h127,256.5)
//   and omz127 = fma(-127,z,127) ready at z (parallel to n-chain); write
//   path after n = fma -> cvt -> ds_write (one fma shorter); h127 =
//   hqf - 256.5 recovers exact fp32 recurrence off-path (err ~2^-24*384).
// Kept from R20: i8 16x16x64 MFMA, exact-bound symmetric quant (|h|<1,
// |W|<1/sqrt(128), h err <= 1/254), i32 accum, dequant in post-select fma,
// exp2/rcp gates, x in LDS + t+1 prefetch, 1 barrier/step.
// Falsified: 4 waves (R21, -8%); pre-barrier pipeline tail (R19, +15%);
// f16 MFMA (R17/18, 2x tiles+chain); fp8 h (e4m3 ~16x h error, absmax risk).

#define BB 256
#define TT 2048
#define HH 128
#define NT 512

typedef int v4i __attribute__((ext_vector_type(4)));

__global__ __launch_bounds__(NT, 1) void gru_seq_kernel(
    const float* __restrict__ x,        // [B, T, 2]
    const int*   __restrict__ lengths,  // [B]
    const float* __restrict__ W_ih,     // [384, 2]
    const float* __restrict__ W_hh,     // [384, 128]
    const float* __restrict__ b_ih,     // [384]
    const float* __restrict__ b_hh,     // [384]
    const float* __restrict__ head_w,   // [128]
    const float* __restrict__ head_b,   // [1]
    float* __restrict__ out)            // [B]
{
    __shared__ __align__(16) float x_lds[(TT + 1) * 2];      // 16 KB (+prefetch pad)
    __shared__ __align__(16) signed char h_lds[2][HH];       // 2 x 128 B, dbuf
    __shared__ float red[HH];

    const int tid = threadIdx.x;
    const int w    = tid >> 6;       // wave 0..7: owns units [16w, 16w+16)
    const int l    = tid & 63;
    const int lg   = l >> 4;         // k-slice (16 i8) / D-row group
    const int m    = l & 15;         // A row within tile = D col (replica id)
    const int rsel = m & 3;          // which D reg this lane consumes
    const int rep  = m >> 2;         // replica 0..3; rep==0 produces
    const int b  = blockIdx.x;
    const int len = lengths[b];

    const float S_RZ = -1.4426950408889634f;   // -log2(e)
    const float S_N  =  2.8853900817779268f;   //  2*log2(e)
    const float WMAX = 0.08838834764831845f;   // 1/sqrt(128), strict |W_hh| bound
    const float QW   = 127.0f / WMAX;          // weight quant scale
    const float CONV = WMAX / 16129.0f;        // dequant: wmax/(127*127)
    const float C_RZ = S_RZ * CONV;
    const float C_N  = S_N * CONV;

    // --- A-frags: afrag[g][c] = int8-packed W_hh[128g+16w+m][64c+16lg+e],
    //     e=0..15 little-endian across 4 dwords. round-half via +256.5 trick.
    v4i afrag[3][2];
    #pragma unroll
    for (int g = 0; g < 3; ++g) {
        const float* Wr = W_hh + (size_t)(128 * g + 16 * w + m) * HH;
        #pragma unroll
        for (int c = 0; c < 2; ++c) {
            unsigned q[4];
            #pragma unroll
            for (int r = 0; r < 4; ++r) {
                q[r] = 0u;
                #pragma unroll
                for (int j = 0; j < 4; ++j) {
                    const float wv = Wr[64 * c + 16 * lg + 4 * r + j];
                    const unsigned bq = ((unsigned)fmaf(wv, QW, 256.5f)) & 0xFFu;
                    q[r] |= bq << (8 * j);
                }
            }
            afrag[g][c] = (v4i){(int)q[0], (int)q[1], (int)q[2], (int)q[3]};
        }
    }

    // --- this lane's unit and per-unit scalars (xp/bias terms, prescaled) ---
    const int u = 16 * w + 4 * lg + rsel;
    const float cr0 = S_RZ * W_ih[u * 2];
    const float cr1 = S_RZ * W_ih[u * 2 + 1];
    const float crb = S_RZ * (b_ih[u] + b_hh[u]);
    const float cz0 = S_RZ * W_ih[(HH + u) * 2];
    const float cz1 = S_RZ * W_ih[(HH + u) * 2 + 1];
    const float czb = S_RZ * (b_ih[HH + u] + b_hh[HH + u]);
    const float cn0 = S_N * W_ih[(2 * HH + u) * 2];
    const float cn1 = S_N * W_ih[(2 * HH + u) * 2 + 1];
    const float cnbi = S_N * b_ih[2 * HH + u];
    const float cnbh = S_N * b_hh[2 * HH + u];
    const float hw127 = head_w[u] * (1.0f / 127.0f);

    // --- stage x[b] into LDS (float4, coalesced) ---
    {
        const float4* xb4 = (const float4*)(x + (size_t)b * TT * 2);
        float4* xl4 = (float4*)x_lds;
        #pragma unroll
        for (int i = tid; i < TT * 2 / 4; i += NT) xl4[i] = xb4[i];
    }
    if (tid == 0) { x_lds[TT * 2] = 0.f; x_lds[TT * 2 + 1] = 0.f; }
    for (int i = tid; i < 2 * HH; i += NT) ((signed char*)h_lds)[i] = 0;

    __syncthreads();

    float h127 = 0.0f;               // fp32 127*h[u]; maintained in all replicas
    int buf = 0;
    const float2* x2 = (const float2*)x_lds;
    float2 xt = x2[0];
    const v4i zero = {0, 0, 0, 0};

    for (int t = 0; t < len; ++t) {
        // h B-frags: 2 x ds_read_b128 (16-lane same-address broadcast)
        const signed char* hb = h_lds[buf];
        const v4i B0 = *(const v4i*)(hb + 16 * lg);        // k 0..63
        const v4i B1 = *(const v4i*)(hb + 64 + 16 * lg);   // k 64..127

        const float2 xt_next = x2[t + 1];   // prefetch (pad-safe at t = len-1)

        // xp terms: independent of h, hide under MFMA phase
        const float xpr = fmaf(cr0, xt.x, fmaf(cr1, xt.y, crb));
        const float xpz = fmaf(cz0, xt.x, fmaf(cz1, xt.y, czb));
        const float xpn = fmaf(cn0, xt.x, fmaf(cn1, xt.y, cnbi));

        // 6 INDEPENDENT 1-deep MFMAs (3 gates x 2 K-halves), 6-way ILP.
        // No C-chaining: combine after select (one MFMA dep-latency less).
        const v4i aR0 = __builtin_amdgcn_mfma_i32_16x16x64_i8(afrag[0][0], B0, zero, 0, 0, 0);
        const v4i aZ0 = __builtin_amdgcn_mfma_i32_16x16x64_i8(afrag[1][0], B0, zero, 0, 0, 0);
        const v4i aN0 = __builtin_amdgcn_mfma_i32_16x16x64_i8(afrag[2][0], B0, zero, 0, 0, 0);
        const v4i aR1 = __builtin_amdgcn_mfma_i32_16x16x64_i8(afrag[0][1], B1, zero, 0, 0, 0);
        const v4i aZ1 = __builtin_amdgcn_mfma_i32_16x16x64_i8(afrag[1][1], B1, zero, 0, 0, 0);
        const v4i aN1 = __builtin_amdgcn_mfma_i32_16x16x64_i8(afrag[2][1], B1, zero, 0, 0, 0);

        // de-replication: 3 cndmask per acc (K-half-0 selects hide under the
        // second MFMA batch), then one i32 add per gate.
        #define PICK(acc) ({                                             \
            const int _v01 = (rsel & 1) ? (acc)[1] : (acc)[0];           \
            const int _v23 = (rsel & 1) ? (acc)[3] : (acc)[2];           \
            (rsel & 2) ? _v23 : _v01; })
        const int sR = PICK(aR0) + PICK(aR1);
        const int sZ = PICK(aZ0) + PICK(aZ1);
        const int sN = PICK(aN0) + PICK(aN1);
        #undef PICK

        // gate chain (dequant+prescale fused):
        // sigmoid(v) = rcp(1+exp2(S_RZ*v)); tanh(y) = 1 - 2*rcp(1+exp2(S_N*y))
        const float ar = fmaf((float)sR, C_RZ, xpr);
        const float az = fmaf((float)sZ, C_RZ, xpz);
        const float r  = __builtin_amdgcn_rcpf(1.f + __builtin_amdgcn_exp2f(ar));
        const float z  = __builtin_amdgcn_rcpf(1.f + __builtin_amdgcn_exp2f(az));
        // ready at z, parallel to the n-chain:
        const float zh127p = fmaf(z, h127, 256.5f);          // z*h127 + round bias
        const float omz127 = fmaf(-127.f, z, 127.f);         // 127*(1-z)
        const float an = fmaf((float)sN, C_N, cnbh);
        const float uu = __builtin_amdgcn_exp2f(fmaf(r, an, xpn));
        const float n  = fmaf(-2.f, __builtin_amdgcn_rcpf(1.f + uu), 1.f);
        // write path after n: ONE fma -> cvt -> ds_write
        const float hqf = fmaf(n, omz127, zh127p);           // 127*h_new + 256.5
        h127 = hqf - 256.5f;                                 // exact, off-path
        if (rep == 0) {
            const unsigned hq = (unsigned)hqf;               // round-half of 127h
            h_lds[buf ^ 1][u] = (signed char)(hq & 0xFFu);
        }
        __syncthreads();
        buf ^= 1;
        xt = xt_next;
    }

    // --- head: out[b] = dot(h, head_w) + head_b ---
    if (rep == 0) red[u] = h127 * hw127;
    __syncthreads();
    if (tid < 64) {
        float v = red[tid] + red[tid + 64];
        #pragma unroll
        for (int off = 32; off > 0; off >>= 1) v += __shfl_xor(v, off, 64);
        if (tid == 0) out[b] = v + head_b[0];
    }
}

extern "C" void kernel_launch(void* const* d_in, const int* in_sizes, int n_in,
                              void* d_out, int out_size, void* d_ws, size_t ws_size,
                              hipStream_t stream) {
    const float* x      = (const float*)d_in[0];
    const int*   len    = (const int*)  d_in[1];
    const float* W_ih   = (const float*)d_in[2];
    const float* W_hh   = (const float*)d_in[3];
    const float* b_ih   = (const float*)d_in[4];
    const float* b_hh   = (const float*)d_in[5];
    const float* head_w = (const float*)d_in[6];
    const float* head_b = (const float*)d_in[7];
    float* out = (float*)d_out;

    gru_seq_kernel<<<BB, NT, 0, stream>>>(x, len, W_ih, W_hh, b_ih, b_hh,
                                          head_w, head_b, out);
}

// Round 7
// 641.139 us; speedup vs baseline: 1.1038x; 1.1038x over previous
//
#include <hip/hip_runtime.h>

// GRU: B=256, T=2048, I=2, H=128. One workgroup (8 waves) per batch element.
// R23 = R20 (verified 628us anchor) + two SAFE shaves. R22 falsified the
// split-MFMA idea: doubling the select tree put ~25cyc of dependent VALU
// after the last MFMA to save ~6cyc of MFMA dep latency (chained-2 is
// nearly free on the half-occupied matrix pipe). Keep R20's chained-2 +
// single 3-cndmask select.
// Shave 1 (from R22, verified absmax-safe): h127-scaled recurrence.
//   omz127 = fma(-127,z,127), zh127p = fma(z,h127,256.5) ready at z, in
//   parallel with the n-chain; post-n path = fma -> cvt -> write (was
//   sub,fma,fma,cvt,write). h127 = hqf-256.5 is EXACT (Sterbenz: hqf in
//   (129.5,383.5) subset [128.25,513]).
// Shave 2: unroll x2 with STATIC buffer indices (no buf^=1), one float4
//   x-read per 2 steps prefetched one iter ahead (replaces 2 float2 reads:
//   one fewer LDS op/step), halved loop overhead. Odd-len tail step.
// Kept from R20: i8 16x16x64 MFMA, 2-deep chained K, exact-bound symmetric
// quant (|h|<1, |W|<1/sqrt(128), h err <= 1/254), i32 accum, dequant in
// post-select fma, exp2/rcp gates, x staged in LDS, 1 barrier/step.
// Falsified: split 1-deep MFMA + double select (R22, +13%); 4 waves (R21,
// +8%); pre-barrier pipeline tail (R19, +15%); f16 MFMA (R17/18: 2x tiles);
// fp8 h exchange (e4m3 ulp at |h|~1 is 0.125 -> absmax blowup).

#define BB 256
#define TT 2048
#define HH 128
#define NT 512

typedef int v4i __attribute__((ext_vector_type(4)));

__global__ __launch_bounds__(NT, 1) void gru_seq_kernel(
    const float* __restrict__ x,        // [B, T, 2]
    const int*   __restrict__ lengths,  // [B]
    const float* __restrict__ W_ih,     // [384, 2]
    const float* __restrict__ W_hh,     // [384, 128]
    const float* __restrict__ b_ih,     // [384]
    const float* __restrict__ b_hh,     // [384]
    const float* __restrict__ head_w,   // [128]
    const float* __restrict__ head_b,   // [1]
    float* __restrict__ out)            // [B]
{
    __shared__ __align__(16) float x_lds[TT * 2 + 4];        // 16 KB + pad pair
    __shared__ __align__(16) signed char h_lds[2][HH];       // 2 x 128 B, dbuf
    __shared__ float red[HH];

    const int tid = threadIdx.x;
    const int w    = tid >> 6;       // wave 0..7: owns units [16w, 16w+16)
    const int l    = tid & 63;
    const int lg   = l >> 4;         // k-slice (16 i8) / D-row group
    const int m    = l & 15;         // A row within tile = D col (replica id)
    const int rsel = m & 3;          // which D reg this lane consumes
    const int rep  = m >> 2;         // replica 0..3; rep==0 produces
    const int b  = blockIdx.x;
    const int len = lengths[b];

    const float S_RZ = -1.4426950408889634f;   // -log2(e)
    const float S_N  =  2.8853900817779268f;   //  2*log2(e)
    const float WMAX = 0.08838834764831845f;   // 1/sqrt(128), strict |W_hh| bound
    const float QW   = 127.0f / WMAX;          // weight quant scale
    const float CONV = WMAX / 16129.0f;        // dequant: wmax/(127*127)
    const float C_RZ = S_RZ * CONV;
    const float C_N  = S_N * CONV;

    // --- A-frags: afrag[g][c] = int8-packed W_hh[128g+16w+m][64c+16lg+e],
    //     e=0..15 little-endian across 4 dwords. round-half via +256.5 trick.
    v4i afrag[3][2];
    #pragma unroll
    for (int g = 0; g < 3; ++g) {
        const float* Wr = W_hh + (size_t)(128 * g + 16 * w + m) * HH;
        #pragma unroll
        for (int c = 0; c < 2; ++c) {
            unsigned q[4];
            #pragma unroll
            for (int r = 0; r < 4; ++r) {
                q[r] = 0u;
                #pragma unroll
                for (int j = 0; j < 4; ++j) {
                    const float wv = Wr[64 * c + 16 * lg + 4 * r + j];
                    const unsigned bq = ((unsigned)fmaf(wv, QW, 256.5f)) & 0xFFu;
                    q[r] |= bq << (8 * j);
                }
            }
            afrag[g][c] = (v4i){(int)q[0], (int)q[1], (int)q[2], (int)q[3]};
        }
    }

    // --- this lane's unit and per-unit scalars (xp/bias terms, prescaled) ---
    const int u = 16 * w + 4 * lg + rsel;
    const float cr0 = S_RZ * W_ih[u * 2];
    const float cr1 = S_RZ * W_ih[u * 2 + 1];
    const float crb = S_RZ * (b_ih[u] + b_hh[u]);
    const float cz0 = S_RZ * W_ih[(HH + u) * 2];
    const float cz1 = S_RZ * W_ih[(HH + u) * 2 + 1];
    const float czb = S_RZ * (b_ih[HH + u] + b_hh[HH + u]);
    const float cn0 = S_N * W_ih[(2 * HH + u) * 2];
    const float cn1 = S_N * W_ih[(2 * HH + u) * 2 + 1];
    const float cnbi = S_N * b_ih[2 * HH + u];
    const float cnbh = S_N * b_hh[2 * HH + u];
    const float hw127 = head_w[u] * (1.0f / 127.0f);

    // --- stage x[b] into LDS (float4, coalesced) ---
    {
        const float4* xb4 = (const float4*)(x + (size_t)b * TT * 2);
        float4* xl4w = (float4*)x_lds;
        #pragma unroll
        for (int i = tid; i < TT * 2 / 4; i += NT) xl4w[i] = xb4[i];
    }
    if (tid < 4) x_lds[TT * 2 + tid] = 0.f;
    for (int i = tid; i < 2 * HH; i += NT) ((signed char*)h_lds)[i] = 0;

    __syncthreads();

    float h127 = 0.0f;               // fp32 127*h[u]; maintained in all replicas
    const v4i zero = {0, 0, 0, 0};

    #define PICK(acc, dst) do {                                          \
        const int _v01 = (rsel & 1) ? (acc)[1] : (acc)[0];               \
        const int _v23 = (rsel & 1) ? (acc)[3] : (acc)[2];               \
        (dst) = (rsel & 2) ? _v23 : _v01; } while (0)

    // One GRU step: read h from h_lds[RB], write h to h_lds[WB], x=(XX,XY).
    #define STEP(RB, WB, XX, XY) do {                                            \
        const signed char* hb = h_lds[RB];                                       \
        const v4i B0 = *(const v4i*)(hb + 16 * lg);        /* k 0..63  */        \
        const v4i B1 = *(const v4i*)(hb + 64 + 16 * lg);   /* k 64..127 */       \
        const float xpr = fmaf(cr0, (XX), fmaf(cr1, (XY), crb));                 \
        const float xpz = fmaf(cz0, (XX), fmaf(cz1, (XY), czb));                 \
        const float xpn = fmaf(cn0, (XX), fmaf(cn1, (XY), cnbi));                \
        v4i accR, accZ, accN;                                                    \
        accR = __builtin_amdgcn_mfma_i32_16x16x64_i8(afrag[0][0], B0, zero, 0, 0, 0); \
        accZ = __builtin_amdgcn_mfma_i32_16x16x64_i8(afrag[1][0], B0, zero, 0, 0, 0); \
        accN = __builtin_amdgcn_mfma_i32_16x16x64_i8(afrag[2][0], B0, zero, 0, 0, 0); \
        accR = __builtin_amdgcn_mfma_i32_16x16x64_i8(afrag[0][1], B1, accR, 0, 0, 0); \
        accZ = __builtin_amdgcn_mfma_i32_16x16x64_i8(afrag[1][1], B1, accZ, 0, 0, 0); \
        accN = __builtin_amdgcn_mfma_i32_16x16x64_i8(afrag[2][1], B1, accN, 0, 0, 0); \
        int sR, sZ, sN;                                                          \
        PICK(accR, sR); PICK(accZ, sZ); PICK(accN, sN);                          \
        const float ar = fmaf((float)sR, C_RZ, xpr);                             \
        const float az = fmaf((float)sZ, C_RZ, xpz);                             \
        const float r  = __builtin_amdgcn_rcpf(1.f + __builtin_amdgcn_exp2f(ar)); \
        const float z  = __builtin_amdgcn_rcpf(1.f + __builtin_amdgcn_exp2f(az)); \
        const float zh127p = fmaf(z, h127, 256.5f);   /* ready at z */           \
        const float omz127 = fmaf(-127.f, z, 127.f);  /* 127*(1-z)  */           \
        const float an = fmaf((float)sN, C_N, cnbh);                             \
        const float uu = __builtin_amdgcn_exp2f(fmaf(r, an, xpn));               \
        const float n  = fmaf(-2.f, __builtin_amdgcn_rcpf(1.f + uu), 1.f);       \
        const float hqf = fmaf(n, omz127, zh127p);    /* 127*h_new + 256.5 */    \
        h127 = hqf - 256.5f;                          /* exact (Sterbenz) */     \
        if (rep == 0) {                                                          \
            const unsigned hq = (unsigned)hqf;        /* round-half of 127h */   \
            h_lds[WB][u] = (signed char)(hq & 0xFFu);                            \
        }                                                                        \
        __syncthreads();                                                         \
    } while (0)

    // --- main loop: unroll x2, static buffers, float4 x pair w/ prefetch ---
    const float4* xl4 = (const float4*)x_lds;
    float4 xc = xl4[0];
    const int len2 = len & ~1;
    for (int t2 = 0; t2 < len2; t2 += 2) {
        const float4 xn = xl4[(t2 >> 1) + 1];   // prefetch next pair (pad-safe)
        STEP(0, 1, xc.x, xc.y);
        STEP(1, 0, xc.z, xc.w);
        xc = xn;
    }
    if (len & 1) STEP(0, 1, xc.x, xc.y);

    #undef STEP
    #undef PICK

    // --- head: out[b] = dot(h, head_w) + head_b ---
    if (rep == 0) red[u] = h127 * hw127;
    __syncthreads();
    if (tid < 64) {
        float v = red[tid] + red[tid + 64];
        #pragma unroll
        for (int off = 32; off > 0; off >>= 1) v += __shfl_xor(v, off, 64);
        if (tid == 0) out[b] = v + head_b[0];
    }
}

extern "C" void kernel_launch(void* const* d_in, const int* in_sizes, int n_in,
                              void* d_out, int out_size, void* d_ws, size_t ws_size,
                              hipStream_t stream) {
    const float* x      = (const float*)d_in[0];
    const int*   len    = (const int*)  d_in[1];
    const float* W_ih   = (const float*)d_in[2];
    const float* W_hh   = (const float*)d_in[3];
    const float* b_ih   = (const float*)d_in[4];
    const float* b_hh   = (const float*)d_in[5];
    const float* head_w = (const float*)d_in[6];
    const float* head_b = (const float*)d_in[7];
    float* out = (float*)d_out;

    gru_seq_kernel<<<BB, NT, 0, stream>>>(x, len, W_ih, W_hh, b_ih, b_hh,
                                          head_w, head_b, out);
}